// Round 12
// baseline (322.276 us; speedup 1.0000x reference)
//
#include <hip/hip_runtime.h>
#include <hip/hip_bf16.h>
#include <math.h>

#define N_NODES 50000
#define N_EDGES 800000
#define IN_C 128
#define HID_C 96
#define OUT_C 64
#define BN_EPS 1e-5f

// ELL edge storage: 64 slots/row. deg ~ Poisson(16); P(deg>64) ~ 1e-17 —
// slot>=64 is guarded (skip) to protect memory, never expected to fire.
#define ELL_SHIFT 6
#define ELL_CAP   64

// XCD routing for the ELL fill (R13 winner; requires a HOMOGENEOUS fill
// kernel — R20 showed fusing with gemm breaks the round-robin heuristic
// and reintroduces 3x write amplification; ledger'd, reverted).
#define NGRP 8
#define GRP_ROWS ((N_NODES + NGRP - 1) / NGRP)   // 6250

// Packed ELL entry: col in low 16 bits (N_NODES < 65536), edge weight as
// 16-bit fixed point in high bits (ew in [0,1); abs err 7.6e-6).
#define EW_SCALE 65535.0f
#define EW_INV   (1.0f / 65535.0f)

// BN stats atomic slicing: 4 slices cut per-address atomic chains 4x.
#define ST_SLICES 4

typedef __attribute__((ext_vector_type(8))) short short8;   // 8 bf16 = 4 VGPRs
typedef __attribute__((ext_vector_type(4))) float f32x4;    // MFMA acc

static __device__ __forceinline__ unsigned short f2b(float f) {
    __hip_bfloat16 b = __float2bfloat16(f);   // RNE
    return *reinterpret_cast<unsigned short*>(&b);
}
static __device__ __forceinline__ float b2f(unsigned short u) {
    return __uint_as_float((unsigned)u << 16);  // exact
}
static __device__ __forceinline__ unsigned pack2(float a, float b) {
    return (unsigned)f2b(a) | ((unsigned)f2b(b) << 16);
}

// Unpack 8 bf16 from a uint4, FMA into acc[B..B+7].
#define FMA8(B, V, W)                                          \
    acc[(B) + 0] += (W) * __uint_as_float((V).x << 16);        \
    acc[(B) + 1] += (W) * __uint_as_float((V).x & 0xffff0000u);\
    acc[(B) + 2] += (W) * __uint_as_float((V).y << 16);        \
    acc[(B) + 3] += (W) * __uint_as_float((V).y & 0xffff0000u);\
    acc[(B) + 4] += (W) * __uint_as_float((V).z << 16);        \
    acc[(B) + 5] += (W) * __uint_as_float((V).z & 0xffff0000u);\
    acc[(B) + 6] += (W) * __uint_as_float((V).w << 16);        \
    acc[(B) + 7] += (W) * __uint_as_float((V).w & 0xffff0000u);

// ---------------------------------------------------------------------------
// Prep (single launch): W[K][J] fp32 -> Wt[J][K] bf16 for all layers, zero
// the ELL counters, zero BN stats (2 buffers x 4 slices x 2*96 floats).
// ---------------------------------------------------------------------------
__global__ void prep_all(const float* __restrict__ W1, const float* __restrict__ W2,
                         const float* __restrict__ W3,
                         unsigned short* __restrict__ Wt1,
                         unsigned short* __restrict__ Wt2,
                         unsigned short* __restrict__ Wt3,
                         int* __restrict__ cnt, float* __restrict__ stats) {
    int i = blockIdx.x * blockDim.x + threadIdx.x;
    const int n1 = IN_C * HID_C, n2 = HID_C * HID_C, n3 = HID_C * OUT_C;
    if (i < n1) {
        int j = i / IN_C, k = i % IN_C;
        Wt1[i] = f2b(W1[k * HID_C + j]);
    } else if (i < n1 + n2) {
        int t = i - n1, j = t / HID_C, k = t % HID_C;
        Wt2[t] = f2b(W2[k * HID_C + j]);
    } else if (i < n1 + n2 + n3) {
        int t = i - n1 - n2, j = t / HID_C, k = t % HID_C;
        Wt3[t] = f2b(W3[k * OUT_C + j]);
    }
    if (i < N_NODES) cnt[i] = 0;
    if (i < 2 * ST_SLICES * 2 * HID_C) stats[i] = 0.f;   // stats1|stats2
}

// ---------------------------------------------------------------------------
// ELL fill, XCD-routed, standalone (R13/R19 winner form).
// ---------------------------------------------------------------------------
__global__ __launch_bounds__(256)
void fill_ell(const int* __restrict__ row, const int* __restrict__ col,
              const float* __restrict__ ew, int* __restrict__ cnt,
              unsigned int* __restrict__ pairs) {
    int g = blockIdx.x & (NGRP - 1);          // row-group -> XCD (heuristic)
    int e = (blockIdx.x >> 3) * 256 + threadIdx.x;
    if (e >= N_EDGES) return;
    int r = row[e];
    int lo = g * GRP_ROWS;
    if ((unsigned)(r - lo) >= (unsigned)GRP_ROWS) return;   // not my group
    int slot = atomicAdd(&cnt[r], 1);
    if (slot < ELL_CAP) {
        unsigned wq = (unsigned)(ew[e] * EW_SCALE + 0.5f);  // [0,1) -> u16
        pairs[((size_t)r << ELL_SHIFT) + slot] = (wq << 16) | (unsigned)col[e];
    }
}

// ---------------------------------------------------------------------------
// MFMA GEMM (R14/R19, unchanged): h[N,J] = x[N,K] @ W[K,J], bf16 LDS
// operands, fp32 accumulate, row-major bf16 h output. XBF16: input table is
// bf16 (layers 2,3); else fp32 (layer 1). Block = 256 threads; tile 64 x J.
// mfma_f32_16x16x32_bf16 layouts (HW-verified):
//   A: lane holds X[m=lane&15][k=(lane>>4)*8+j]
//   B: lane holds W[k=(lane>>4)*8+j][n=lane&15]
//   D: lane,reg r -> row m=(lane>>4)*4+r, col n=lane&15
// APPLY: previous layer's BN finalize+apply+ReLU fused into x staging
// (conv bias cancels inside BN); stats arrive as ST_SLICES partials.
// ---------------------------------------------------------------------------
template <int K, int J, bool APPLY, bool XBF16>
__global__ __launch_bounds__(256)
void gemm_mfma(const void* __restrict__ xin,
               const unsigned short* __restrict__ Wt,  // [J][K] bf16
               const float* __restrict__ stats,
               const float* __restrict__ gamma,
               const float* __restrict__ beta,
               unsigned short* __restrict__ h, int N) {
    constexpr int MT = 64;
    constexpr int SK = K + 8;
    constexpr int NT = J / 16;
    __shared__ unsigned short Xs[MT * SK];
    __shared__ unsigned short Ws[J * SK];
    __shared__ float scsh_s[APPLY ? 2 * K : 2];

    int tid = threadIdx.x;
    int tileBase = blockIdx.x * MT;

    if (APPLY) {
        if (tid < K) {
            float s = 0.f, sq = 0.f;
#pragma unroll
            for (int sl = 0; sl < ST_SLICES; ++sl) {
                s  += stats[sl * 2 * K + tid];
                sq += stats[sl * 2 * K + K + tid];
            }
            const float invN = 1.f / N_NODES;
            float mean = s * invN;
            float var = sq * invN - mean * mean;
            float sc = gamma[tid] * rsqrtf(var + BN_EPS);
            scsh_s[tid] = sc;
            scsh_s[K + tid] = beta[tid] - mean * sc;
        }
        __syncthreads();
    }

    if (XBF16) {
        const unsigned short* xb = (const unsigned short*)xin;
        for (int i = tid; i < MT * (K / 8); i += 256) {
            int node = i / (K / 8), kq = i % (K / 8);
            int gn = min(tileBase + node, N - 1);
            const unsigned short* src = xb + (size_t)gn * K + kq * 8;
            ushort4 u0 = *(const ushort4*)(src);
            ushort4 u1 = *(const ushort4*)(src + 4);
            if (APPLY) {
                int kb = kq * 8;
                float v0 = fmaxf(b2f(u0.x) * scsh_s[kb + 0] + scsh_s[K + kb + 0], 0.f);
                float v1 = fmaxf(b2f(u0.y) * scsh_s[kb + 1] + scsh_s[K + kb + 1], 0.f);
                float v2 = fmaxf(b2f(u0.z) * scsh_s[kb + 2] + scsh_s[K + kb + 2], 0.f);
                float v3 = fmaxf(b2f(u0.w) * scsh_s[kb + 3] + scsh_s[K + kb + 3], 0.f);
                float v4 = fmaxf(b2f(u1.x) * scsh_s[kb + 4] + scsh_s[K + kb + 4], 0.f);
                float v5 = fmaxf(b2f(u1.y) * scsh_s[kb + 5] + scsh_s[K + kb + 5], 0.f);
                float v6 = fmaxf(b2f(u1.z) * scsh_s[kb + 6] + scsh_s[K + kb + 6], 0.f);
                float v7 = fmaxf(b2f(u1.w) * scsh_s[kb + 7] + scsh_s[K + kb + 7], 0.f);
                u0 = make_ushort4(f2b(v0), f2b(v1), f2b(v2), f2b(v3));
                u1 = make_ushort4(f2b(v4), f2b(v5), f2b(v6), f2b(v7));
            }
            *(ushort4*)&Xs[node * SK + kq * 8] = u0;
            *(ushort4*)&Xs[node * SK + kq * 8 + 4] = u1;
        }
    } else {
        const float* xf = (const float*)xin;
        for (int i = tid; i < MT * (K / 4); i += 256) {
            int node = i / (K / 4), kq = i % (K / 4);
            int gn = min(tileBase + node, N - 1);
            float4 v = *(const float4*)(xf + (size_t)gn * K + kq * 4);
            ushort4 o = make_ushort4(f2b(v.x), f2b(v.y), f2b(v.z), f2b(v.w));
            *(ushort4*)&Xs[node * SK + kq * 4] = o;
        }
    }
    for (int i = tid; i < J * (K / 4); i += 256) {
        int j = i / (K / 4), kq = i % (K / 4);
        *(ushort4*)&Ws[j * SK + kq * 4] =
            *(const ushort4*)(Wt + (size_t)j * K + kq * 4);
    }
    __syncthreads();

    int lane = tid & 63;
    int w = tid >> 6;
    int m16 = lane & 15;
    int quad = lane >> 4;

    f32x4 acc[NT];
#pragma unroll
    for (int nt = 0; nt < NT; ++nt) acc[nt] = (f32x4){0.f, 0.f, 0.f, 0.f};

    const unsigned short* xrow = &Xs[(w * 16 + m16) * SK];
#pragma unroll
    for (int k0 = 0; k0 < K; k0 += 32) {
        short8 a = *(const short8*)(xrow + k0 + quad * 8);
#pragma unroll
        for (int nt = 0; nt < NT; ++nt) {
            short8 b = *(const short8*)&Ws[(nt * 16 + m16) * SK + k0 + quad * 8];
            acc[nt] = __builtin_amdgcn_mfma_f32_16x16x32_bf16(a, b, acc[nt], 0, 0, 0);
        }
    }

#pragma unroll
    for (int nt = 0; nt < NT; ++nt) {
#pragma unroll
        for (int r = 0; r < 4; ++r) {
            int node = tileBase + w * 16 + quad * 4 + r;
            if (node < N)
                h[(size_t)node * J + nt * 16 + m16] = f2b(acc[nt][r]);
        }
    }
}

// ---------------------------------------------------------------------------
// R21: 96-ch aggregation, 12 threads/node (C=8), ONE uint4 h-load per edge.
// Rationale: R19's MLP-increase null implies the agg is REQUEST-throughput
// bound, not latency-bound. Old layout (8 lanes x 3 uint2 at 24B stride)
// issued 3 wave-instructions per edge, each touching the SAME 3 cache lines
// of the 192B row -> 9 line-requests/edge. Now 12 lanes x 16B cover the row
// in ONE instruction -> 3 requests/edge (the minimum; rows are 64B-aligned:
// 192 = 3x64). VMEM instructions/edge drop 3x, addressing VALU ~halves.
// Wave = 5 nodes x 12 lanes (lanes 60-63 idle, 6% waste). 20 nodes/block ->
// grid 2500 (~9.8 blocks/CU) -> full 32 waves/CU; launch_bounds(256,8)
// pins VGPR<=64 so occupancy holds. BN stats via LDS-atomic accumulation
// (12-lane groups break the XOR butterfly; 96 slots x ~20-deep is cheap).
// ---------------------------------------------------------------------------
__global__ __launch_bounds__(256, 8)
void agg96(const unsigned short* __restrict__ h,     // row-major [N][96]
           const int* __restrict__ cnt,
           const unsigned int* __restrict__ pairs,
           unsigned short* __restrict__ outb,        // row-major [N][96]
           float* __restrict__ stats) {
    constexpr int D = HID_C;          // 96
    int tid = threadIdx.x;
    int wv = tid >> 6, lane = tid & 63;
    int nl = lane / 12;               // 0..4 valid; 5 => idle (lanes 60-63)
    int q = lane - nl * 12;           // 0..11
    int n = blockIdx.x * 20 + wv * 5 + nl;
    bool valid = (nl < 5) && (n < N_NODES);
    int nn = valid ? n : 0;
    int end = valid ? min(cnt[nn], ELL_CAP) : 0;
    const unsigned* ep = pairs + ((size_t)nn << ELL_SHIFT);
    const int cbase = q * 8;          // channels [q*8, q*8+8); byte off q*16

    float acc[8];
#pragma unroll
    for (int c = 0; c < 8; ++c) acc[c] = 0.f;

    int i = 0;
    for (; i + 3 < end; i += 4) {
        uint2 pa = *(const uint2*)(ep + i);       // edges i, i+1 (broadcast)
        uint2 pb = *(const uint2*)(ep + i + 2);   // edges i+2, i+3
        float w0 = (float)(pa.x >> 16) * EW_INV;
        float w1 = (float)(pa.y >> 16) * EW_INV;
        float w2 = (float)(pb.x >> 16) * EW_INV;
        float w3 = (float)(pb.y >> 16) * EW_INV;
        // One 16B load per edge: 12 lanes cover the full 192B row.
        uint4 v0 = *(const uint4*)(h + (size_t)(pa.x & 0xFFFFu) * D + cbase);
        uint4 v1 = *(const uint4*)(h + (size_t)(pa.y & 0xFFFFu) * D + cbase);
        uint4 v2 = *(const uint4*)(h + (size_t)(pb.x & 0xFFFFu) * D + cbase);
        uint4 v3 = *(const uint4*)(h + (size_t)(pb.y & 0xFFFFu) * D + cbase);
        FMA8(0, v0, w0)
        FMA8(0, v1, w1)
        FMA8(0, v2, w2)
        FMA8(0, v3, w3)
    }
    for (; i < end; ++i) {
        unsigned p = ep[i];
        float w = (float)(p >> 16) * EW_INV;
        uint4 v = *(const uint4*)(h + (size_t)(p & 0xFFFFu) * D + cbase);
        FMA8(0, v, w)
    }

    // Round to bf16 in place (stats must see the rounded values).
#pragma unroll
    for (int c = 0; c < 8; ++c) acc[c] = b2f(f2b(acc[c]));

    if (valid) {
        uint4 o;
        o.x = pack2(acc[0], acc[1]);
        o.y = pack2(acc[2], acc[3]);
        o.z = pack2(acc[4], acc[5]);
        o.w = pack2(acc[6], acc[7]);
        *(uint4*)(outb + (size_t)n * D + cbase) = o;   // one 16B store
    }

    // BN stats: LDS-atomic accumulate (20 adds/slot max), then one sliced
    // global atomicAdd per channel per block.
    __shared__ float shS[D];
    __shared__ float shQ[D];
    if (tid < D) { shS[tid] = 0.f; shQ[tid] = 0.f; }
    __syncthreads();
    if (valid) {
#pragma unroll
        for (int c = 0; c < 8; ++c) {
            atomicAdd(&shS[cbase + c], acc[c]);
            atomicAdd(&shQ[cbase + c], acc[c] * acc[c]);
        }
    }
    __syncthreads();
    if (tid < D) {
        int sl = blockIdx.x & (ST_SLICES - 1);
        atomicAdd(&stats[sl * 2 * D + tid], shS[tid]);
        atomicAdd(&stats[sl * 2 * D + D + tid], shQ[tid]);
    }
}

// ---------------------------------------------------------------------------
// Layer-3 aggregation + b3 + log_softmax (R19, unchanged — its one-uint4-
// per-edge layout is already at the 2-requests/edge minimum for 128B rows).
// ---------------------------------------------------------------------------
__global__ __launch_bounds__(256, 6)
void agg64_lsm(const unsigned short* __restrict__ h,  // row-major [N][64]
               const int* __restrict__ cnt,
               const unsigned int* __restrict__ pairs,
               float* __restrict__ outf,
               const float* __restrict__ b3) {
    constexpr int D = OUT_C, C = 8;
    int tid = threadIdx.x;
    int q = tid & 7;
    int nloc = tid >> 3;              // 0..31
    int n = blockIdx.x * 32 + nloc;
    bool valid = n < N_NODES;
    int nn = valid ? n : N_NODES - 1;
    int end = valid ? min(cnt[nn], ELL_CAP) : 0;
    const unsigned* ep = pairs + ((size_t)nn << ELL_SHIFT);
    const int cbase = q * C;          // byte offset q*16: 16B-aligned

    float acc[C];
#pragma unroll
    for (int c = 0; c < C; ++c) acc[c] = 0.f;

    int i = 0;
    for (; i + 5 < end; i += 6) {
        uint2 pa = *(const uint2*)(ep + i);
        uint2 pb = *(const uint2*)(ep + i + 2);
        uint2 pc = *(const uint2*)(ep + i + 4);
        float w0 = (float)(pa.x >> 16) * EW_INV;
        float w1 = (float)(pa.y >> 16) * EW_INV;
        float w2 = (float)(pb.x >> 16) * EW_INV;
        float w3 = (float)(pb.y >> 16) * EW_INV;
        float w4 = (float)(pc.x >> 16) * EW_INV;
        float w5 = (float)(pc.y >> 16) * EW_INV;
        uint4 v0 = *(const uint4*)(h + (size_t)(pa.x & 0xFFFFu) * D + cbase);
        uint4 v1 = *(const uint4*)(h + (size_t)(pa.y & 0xFFFFu) * D + cbase);
        uint4 v2 = *(const uint4*)(h + (size_t)(pb.x & 0xFFFFu) * D + cbase);
        uint4 v3 = *(const uint4*)(h + (size_t)(pb.y & 0xFFFFu) * D + cbase);
        uint4 v4 = *(const uint4*)(h + (size_t)(pc.x & 0xFFFFu) * D + cbase);
        uint4 v5 = *(const uint4*)(h + (size_t)(pc.y & 0xFFFFu) * D + cbase);
        FMA8(0, v0, w0)
        FMA8(0, v1, w1)
        FMA8(0, v2, w2)
        FMA8(0, v3, w3)
        FMA8(0, v4, w4)
        FMA8(0, v5, w5)
    }
    for (; i < end; ++i) {
        unsigned p = ep[i];
        float w = (float)(p >> 16) * EW_INV;
        uint4 v = *(const uint4*)(h + (size_t)(p & 0xFFFFu) * D + cbase);
        FMA8(0, v, w)
    }

    float v[C];
#pragma unroll
    for (int c = 0; c < C; ++c) v[c] = acc[c] + b3[cbase + c];
    float m = v[0];
#pragma unroll
    for (int c = 1; c < C; ++c) m = fmaxf(m, v[c]);
    m = fmaxf(m, __shfl_xor(m, 1));
    m = fmaxf(m, __shfl_xor(m, 2));
    m = fmaxf(m, __shfl_xor(m, 4));
    float s = 0.f;
#pragma unroll
    for (int c = 0; c < C; ++c) s += expf(v[c] - m);
    s += __shfl_xor(s, 1);
    s += __shfl_xor(s, 2);
    s += __shfl_xor(s, 4);
    float l = m + logf(s);
    if (valid) {
        float4 o0 = make_float4(v[0] - l, v[1] - l, v[2] - l, v[3] - l);
        float4 o1 = make_float4(v[4] - l, v[5] - l, v[6] - l, v[7] - l);
        float* dst = outf + (size_t)n * D + cbase;
        *(float4*)(dst) = o0;
        *(float4*)(dst + 4) = o1;
    }
}

extern "C" void kernel_launch(void* const* d_in, const int* in_sizes, int n_in,
                              void* d_out, int out_size, void* d_ws, size_t ws_size,
                              hipStream_t stream) {
    const float* x   = (const float*)d_in[0];
    const float* ew  = (const float*)d_in[1];
    const int*   row = (const int*)d_in[2];
    const int*   col = (const int*)d_in[3];
    const float* W1  = (const float*)d_in[4];
    // b1 = d_in[5], b2 = d_in[7]: cancel inside BatchNorm (see gemm_mfma).
    const float* W2  = (const float*)d_in[6];
    const float* W3  = (const float*)d_in[8];
    const float* b3  = (const float*)d_in[9];
    const float* g1  = (const float*)d_in[10];
    const float* be1 = (const float*)d_in[11];
    const float* g2  = (const float*)d_in[12];
    const float* be2 = (const float*)d_in[13];
    float* out = (float*)d_out;

    // Workspace layout:
    // B bf16[N*96] | A bf16[N*96] | Wt1|Wt2|Wt3 bf16 | pairs uint[N*64] |
    // cnt[N] | stats1[4*192] | stats2[4*192]
    unsigned short* B      = (unsigned short*)d_ws;
    unsigned short* A      = B + (size_t)N_NODES * HID_C;
    unsigned short* Wt1    = A + (size_t)N_NODES * HID_C;
    unsigned short* Wt2    = Wt1 + IN_C * HID_C;
    unsigned short* Wt3    = Wt2 + HID_C * HID_C;
    unsigned int*   pairs  = (unsigned int*)(Wt3 + HID_C * OUT_C);
    int*            cnt    = (int*)(pairs + ((size_t)N_NODES << ELL_SHIFT));
    float*          stats1 = (float*)(cnt + N_NODES);
    float*          stats2 = stats1 + ST_SLICES * 2 * HID_C;

    const int T = 256;
    const int gridE  = (N_EDGES + T - 1) / T;        // 3125 edge chunks
    const int gridG  = (N_NODES + 63) / 64;          // 782 gemm tiles
    const int gridA9 = (N_NODES + 19) / 20;          // 2500 agg96 blocks (R21)
    const int gridA6 = (N_NODES + 31) / 32;          // 1563 agg64 blocks
    const int gridP  = (N_NODES + T - 1) / T;

    // ---- Prep + fill (standalone: keeps the XCD round-robin intact) ----
    prep_all<<<gridP, T, 0, stream>>>(W1, W2, W3, Wt1, Wt2, Wt3, cnt, stats1);
    fill_ell<<<gridE * NGRP, T, 0, stream>>>(row, col, ew, cnt, pairs);

    // ---- Layer 1: gemm(128->96); agg(+BN1 stats) ----
    gemm_mfma<IN_C, HID_C, false, false><<<gridG, T, 0, stream>>>(
        x, Wt1, nullptr, nullptr, nullptr, A, N_NODES);
    agg96<<<gridA9, T, 0, stream>>>(A, cnt, pairs, B, stats1);

    // ---- Layer 2: gemm fuses BN1 finalize+apply+ReLU; agg(+BN2 stats) ----
    gemm_mfma<HID_C, HID_C, true, true><<<gridG, T, 0, stream>>>(
        B, Wt2, stats1, g1, be1, A, N_NODES);
    agg96<<<gridA9, T, 0, stream>>>(A, cnt, pairs, B, stats2);

    // ---- Layer 3: gemm fuses BN2; agg fuses +b3 and log_softmax -> out ----
    gemm_mfma<HID_C, OUT_C, true, true><<<gridG, T, 0, stream>>>(
        B, Wt3, stats2, g2, be2, A, N_NODES);
    agg64_lsm<<<gridA6, T, 0, stream>>>(A, cnt, pairs, out, b3);
}

// Round 13
// 321.862 us; speedup vs baseline: 1.0013x; 1.0013x over previous
//
#include <hip/hip_runtime.h>
#include <hip/hip_bf16.h>
#include <math.h>

#define N_NODES 50000
#define N_EDGES 800000
#define IN_C 128
#define HID_C 96
#define OUT_C 64
#define BN_EPS 1e-5f

// ELL edge storage: 64 slots/row. deg ~ Poisson(16); P(deg>64) ~ 1e-17 —
// slot>=64 is guarded (skip) to protect memory, never expected to fire.
#define ELL_SHIFT 6
#define ELL_CAP   64

// XCD routing for the ELL fill (R13 winner; requires a HOMOGENEOUS fill
// kernel — R20 showed fusing with gemm breaks the round-robin heuristic).
#define NGRP 8
#define GRP_ROWS ((N_NODES + NGRP - 1) / NGRP)   // 6250

// Packed ELL entry: col in low 16 bits (N_NODES < 65536), edge weight as
// 16-bit fixed point in high bits (ew in [0,1); abs err 7.6e-6).
#define EW_SCALE 65535.0f
#define EW_INV   (1.0f / 65535.0f)

// BN stats atomic slicing: 4 slices cut per-address atomic chains 4x.
#define ST_SLICES 4

typedef __attribute__((ext_vector_type(8))) short short8;   // 8 bf16 = 4 VGPRs
typedef __attribute__((ext_vector_type(4))) float f32x4;    // MFMA acc

static __device__ __forceinline__ unsigned short f2b(float f) {
    __hip_bfloat16 b = __float2bfloat16(f);   // RNE
    return *reinterpret_cast<unsigned short*>(&b);
}
static __device__ __forceinline__ float b2f(unsigned short u) {
    return __uint_as_float((unsigned)u << 16);  // exact
}
static __device__ __forceinline__ unsigned pack2(float a, float b) {
    return (unsigned)f2b(a) | ((unsigned)f2b(b) << 16);
}

// Unpack 8 bf16 from a uint4, FMA into acc[B..B+7].
#define FMA8(B, V, W)                                          \
    acc[(B) + 0] += (W) * __uint_as_float((V).x << 16);        \
    acc[(B) + 1] += (W) * __uint_as_float((V).x & 0xffff0000u);\
    acc[(B) + 2] += (W) * __uint_as_float((V).y << 16);        \
    acc[(B) + 3] += (W) * __uint_as_float((V).y & 0xffff0000u);\
    acc[(B) + 4] += (W) * __uint_as_float((V).z << 16);        \
    acc[(B) + 5] += (W) * __uint_as_float((V).z & 0xffff0000u);\
    acc[(B) + 6] += (W) * __uint_as_float((V).w << 16);        \
    acc[(B) + 7] += (W) * __uint_as_float((V).w & 0xffff0000u);

// ---------------------------------------------------------------------------
// Prep (single launch): W[K][J] fp32 -> Wt[J][K] bf16 for all layers, zero
// the ELL counters, zero BN stats (2 buffers x 4 slices x 2*96 floats).
// ---------------------------------------------------------------------------
__global__ void prep_all(const float* __restrict__ W1, const float* __restrict__ W2,
                         const float* __restrict__ W3,
                         unsigned short* __restrict__ Wt1,
                         unsigned short* __restrict__ Wt2,
                         unsigned short* __restrict__ Wt3,
                         int* __restrict__ cnt, float* __restrict__ stats) {
    int i = blockIdx.x * blockDim.x + threadIdx.x;
    const int n1 = IN_C * HID_C, n2 = HID_C * HID_C, n3 = HID_C * OUT_C;
    if (i < n1) {
        int j = i / IN_C, k = i % IN_C;
        Wt1[i] = f2b(W1[k * HID_C + j]);
    } else if (i < n1 + n2) {
        int t = i - n1, j = t / HID_C, k = t % HID_C;
        Wt2[t] = f2b(W2[k * HID_C + j]);
    } else if (i < n1 + n2 + n3) {
        int t = i - n1 - n2, j = t / HID_C, k = t % HID_C;
        Wt3[t] = f2b(W3[k * OUT_C + j]);
    }
    if (i < N_NODES) cnt[i] = 0;
    if (i < 2 * ST_SLICES * 2 * HID_C) stats[i] = 0.f;   // stats1|stats2
}

// ---------------------------------------------------------------------------
// ELL fill, XCD-routed, standalone (R13/R19 winner form).
// ---------------------------------------------------------------------------
__global__ __launch_bounds__(256)
void fill_ell(const int* __restrict__ row, const int* __restrict__ col,
              const float* __restrict__ ew, int* __restrict__ cnt,
              unsigned int* __restrict__ pairs) {
    int g = blockIdx.x & (NGRP - 1);          // row-group -> XCD (heuristic)
    int e = (blockIdx.x >> 3) * 256 + threadIdx.x;
    if (e >= N_EDGES) return;
    int r = row[e];
    int lo = g * GRP_ROWS;
    if ((unsigned)(r - lo) >= (unsigned)GRP_ROWS) return;   // not my group
    int slot = atomicAdd(&cnt[r], 1);
    if (slot < ELL_CAP) {
        unsigned wq = (unsigned)(ew[e] * EW_SCALE + 0.5f);  // [0,1) -> u16
        pairs[((size_t)r << ELL_SHIFT) + slot] = (wq << 16) | (unsigned)col[e];
    }
}

// ---------------------------------------------------------------------------
// MFMA GEMM (R14/R19, unchanged): h[N,J] = x[N,K] @ W[K,J], bf16 LDS
// operands, fp32 accumulate, row-major bf16 h output. XBF16: input table is
// bf16 (layers 2,3); else fp32 (layer 1). Block = 256 threads; tile 64 x J.
// mfma_f32_16x16x32_bf16 layouts (HW-verified):
//   A: lane holds X[m=lane&15][k=(lane>>4)*8+j]
//   B: lane holds W[k=(lane>>4)*8+j][n=lane&15]
//   D: lane,reg r -> row m=(lane>>4)*4+r, col n=lane&15
// APPLY: previous layer's BN finalize+apply+ReLU fused into x staging
// (conv bias cancels inside BN); stats arrive as ST_SLICES partials.
// ---------------------------------------------------------------------------
template <int K, int J, bool APPLY, bool XBF16>
__global__ __launch_bounds__(256)
void gemm_mfma(const void* __restrict__ xin,
               const unsigned short* __restrict__ Wt,  // [J][K] bf16
               const float* __restrict__ stats,
               const float* __restrict__ gamma,
               const float* __restrict__ beta,
               unsigned short* __restrict__ h, int N) {
    constexpr int MT = 64;
    constexpr int SK = K + 8;
    constexpr int NT = J / 16;
    __shared__ unsigned short Xs[MT * SK];
    __shared__ unsigned short Ws[J * SK];
    __shared__ float scsh_s[APPLY ? 2 * K : 2];

    int tid = threadIdx.x;
    int tileBase = blockIdx.x * MT;

    if (APPLY) {
        if (tid < K) {
            float s = 0.f, sq = 0.f;
#pragma unroll
            for (int sl = 0; sl < ST_SLICES; ++sl) {
                s  += stats[sl * 2 * K + tid];
                sq += stats[sl * 2 * K + K + tid];
            }
            const float invN = 1.f / N_NODES;
            float mean = s * invN;
            float var = sq * invN - mean * mean;
            float sc = gamma[tid] * rsqrtf(var + BN_EPS);
            scsh_s[tid] = sc;
            scsh_s[K + tid] = beta[tid] - mean * sc;
        }
        __syncthreads();
    }

    if (XBF16) {
        const unsigned short* xb = (const unsigned short*)xin;
        for (int i = tid; i < MT * (K / 8); i += 256) {
            int node = i / (K / 8), kq = i % (K / 8);
            int gn = min(tileBase + node, N - 1);
            const unsigned short* src = xb + (size_t)gn * K + kq * 8;
            ushort4 u0 = *(const ushort4*)(src);
            ushort4 u1 = *(const ushort4*)(src + 4);
            if (APPLY) {
                int kb = kq * 8;
                float v0 = fmaxf(b2f(u0.x) * scsh_s[kb + 0] + scsh_s[K + kb + 0], 0.f);
                float v1 = fmaxf(b2f(u0.y) * scsh_s[kb + 1] + scsh_s[K + kb + 1], 0.f);
                float v2 = fmaxf(b2f(u0.z) * scsh_s[kb + 2] + scsh_s[K + kb + 2], 0.f);
                float v3 = fmaxf(b2f(u0.w) * scsh_s[kb + 3] + scsh_s[K + kb + 3], 0.f);
                float v4 = fmaxf(b2f(u1.x) * scsh_s[kb + 4] + scsh_s[K + kb + 4], 0.f);
                float v5 = fmaxf(b2f(u1.y) * scsh_s[kb + 5] + scsh_s[K + kb + 5], 0.f);
                float v6 = fmaxf(b2f(u1.z) * scsh_s[kb + 6] + scsh_s[K + kb + 6], 0.f);
                float v7 = fmaxf(b2f(u1.w) * scsh_s[kb + 7] + scsh_s[K + kb + 7], 0.f);
                u0 = make_ushort4(f2b(v0), f2b(v1), f2b(v2), f2b(v3));
                u1 = make_ushort4(f2b(v4), f2b(v5), f2b(v6), f2b(v7));
            }
            *(ushort4*)&Xs[node * SK + kq * 8] = u0;
            *(ushort4*)&Xs[node * SK + kq * 8 + 4] = u1;
        }
    } else {
        const float* xf = (const float*)xin;
        for (int i = tid; i < MT * (K / 4); i += 256) {
            int node = i / (K / 4), kq = i % (K / 4);
            int gn = min(tileBase + node, N - 1);
            float4 v = *(const float4*)(xf + (size_t)gn * K + kq * 4);
            ushort4 o = make_ushort4(f2b(v.x), f2b(v.y), f2b(v.z), f2b(v.w));
            *(ushort4*)&Xs[node * SK + kq * 4] = o;
        }
    }
    for (int i = tid; i < J * (K / 4); i += 256) {
        int j = i / (K / 4), kq = i % (K / 4);
        *(ushort4*)&Ws[j * SK + kq * 4] =
            *(const ushort4*)(Wt + (size_t)j * K + kq * 4);
    }
    __syncthreads();

    int lane = tid & 63;
    int w = tid >> 6;
    int m16 = lane & 15;
    int quad = lane >> 4;

    f32x4 acc[NT];
#pragma unroll
    for (int nt = 0; nt < NT; ++nt) acc[nt] = (f32x4){0.f, 0.f, 0.f, 0.f};

    const unsigned short* xrow = &Xs[(w * 16 + m16) * SK];
#pragma unroll
    for (int k0 = 0; k0 < K; k0 += 32) {
        short8 a = *(const short8*)(xrow + k0 + quad * 8);
#pragma unroll
        for (int nt = 0; nt < NT; ++nt) {
            short8 b = *(const short8*)&Ws[(nt * 16 + m16) * SK + k0 + quad * 8];
            acc[nt] = __builtin_amdgcn_mfma_f32_16x16x32_bf16(a, b, acc[nt], 0, 0, 0);
        }
    }

#pragma unroll
    for (int nt = 0; nt < NT; ++nt) {
#pragma unroll
        for (int r = 0; r < 4; ++r) {
            int node = tileBase + w * 16 + quad * 4 + r;
            if (node < N)
                h[(size_t)node * J + nt * 16 + m16] = f2b(acc[nt][r]);
        }
    }
}

// ---------------------------------------------------------------------------
// R22: 96-ch aggregation = R21 structure (12 threads/node, one uint4 per
// 192B row per edge = minimum 3 line-requests) with the VGPR squeeze fixed.
// R21's launch_bounds(256,8) forced VGPR=28 (counter-verified) -> compiler
// serialized the 4 in-flight loads (needs ~16 VGPRs co-live) -> 68us, worse
// than R17's ~40. FETCH was layout-invariant (~70MB, same as R16's agg), so
// the regression was in-kernel issue serialization, not memory traffic.
// (256,4) gives a 128-VGPR budget: loads overlap again. Single-variable
// retest of the request-count theory.
// ---------------------------------------------------------------------------
__global__ __launch_bounds__(256, 4)
void agg96(const unsigned short* __restrict__ h,     // row-major [N][96]
           const int* __restrict__ cnt,
           const unsigned int* __restrict__ pairs,
           unsigned short* __restrict__ outb,        // row-major [N][96]
           float* __restrict__ stats) {
    constexpr int D = HID_C;          // 96
    int tid = threadIdx.x;
    int wv = tid >> 6, lane = tid & 63;
    int nl = lane / 12;               // 0..4 valid; 5 => idle (lanes 60-63)
    int q = lane - nl * 12;           // 0..11
    int n = blockIdx.x * 20 + wv * 5 + nl;
    bool valid = (nl < 5) && (n < N_NODES);
    int nn = valid ? n : 0;
    int end = valid ? min(cnt[nn], ELL_CAP) : 0;
    const unsigned* ep = pairs + ((size_t)nn << ELL_SHIFT);
    const int cbase = q * 8;          // channels [q*8, q*8+8); byte off q*16

    float acc[8];
#pragma unroll
    for (int c = 0; c < 8; ++c) acc[c] = 0.f;

    int i = 0;
    for (; i + 3 < end; i += 4) {
        uint2 pa = *(const uint2*)(ep + i);       // edges i, i+1 (broadcast)
        uint2 pb = *(const uint2*)(ep + i + 2);   // edges i+2, i+3
        float w0 = (float)(pa.x >> 16) * EW_INV;
        float w1 = (float)(pa.y >> 16) * EW_INV;
        float w2 = (float)(pb.x >> 16) * EW_INV;
        float w3 = (float)(pb.y >> 16) * EW_INV;
        // One 16B load per edge: 12 lanes cover the full 192B row.
        uint4 v0 = *(const uint4*)(h + (size_t)(pa.x & 0xFFFFu) * D + cbase);
        uint4 v1 = *(const uint4*)(h + (size_t)(pa.y & 0xFFFFu) * D + cbase);
        uint4 v2 = *(const uint4*)(h + (size_t)(pb.x & 0xFFFFu) * D + cbase);
        uint4 v3 = *(const uint4*)(h + (size_t)(pb.y & 0xFFFFu) * D + cbase);
        FMA8(0, v0, w0)
        FMA8(0, v1, w1)
        FMA8(0, v2, w2)
        FMA8(0, v3, w3)
    }
    for (; i < end; ++i) {
        unsigned p = ep[i];
        float w = (float)(p >> 16) * EW_INV;
        uint4 v = *(const uint4*)(h + (size_t)(p & 0xFFFFu) * D + cbase);
        FMA8(0, v, w)
    }

    // Round to bf16 in place (stats must see the rounded values).
#pragma unroll
    for (int c = 0; c < 8; ++c) acc[c] = b2f(f2b(acc[c]));

    if (valid) {
        uint4 o;
        o.x = pack2(acc[0], acc[1]);
        o.y = pack2(acc[2], acc[3]);
        o.z = pack2(acc[4], acc[5]);
        o.w = pack2(acc[6], acc[7]);
        *(uint4*)(outb + (size_t)n * D + cbase) = o;   // one 16B store
    }

    // BN stats: LDS-atomic accumulate (20 adds/slot max), then one sliced
    // global atomicAdd per channel per block.
    __shared__ float shS[D];
    __shared__ float shQ[D];
    if (tid < D) { shS[tid] = 0.f; shQ[tid] = 0.f; }
    __syncthreads();
    if (valid) {
#pragma unroll
        for (int c = 0; c < 8; ++c) {
            atomicAdd(&shS[cbase + c], acc[c]);
            atomicAdd(&shQ[cbase + c], acc[c] * acc[c]);
        }
    }
    __syncthreads();
    if (tid < D) {
        int sl = blockIdx.x & (ST_SLICES - 1);
        atomicAdd(&stats[sl * 2 * D + tid], shS[tid]);
        atomicAdd(&stats[sl * 2 * D + D + tid], shQ[tid]);
    }
}

// ---------------------------------------------------------------------------
// Layer-3 aggregation + b3 + log_softmax (R19, unchanged — its one-uint4-
// per-edge layout is already at the 2-requests/edge minimum for 128B rows).
// ---------------------------------------------------------------------------
__global__ __launch_bounds__(256, 6)
void agg64_lsm(const unsigned short* __restrict__ h,  // row-major [N][64]
               const int* __restrict__ cnt,
               const unsigned int* __restrict__ pairs,
               float* __restrict__ outf,
               const float* __restrict__ b3) {
    constexpr int D = OUT_C, C = 8;
    int tid = threadIdx.x;
    int q = tid & 7;
    int nloc = tid >> 3;              // 0..31
    int n = blockIdx.x * 32 + nloc;
    bool valid = n < N_NODES;
    int nn = valid ? n : N_NODES - 1;
    int end = valid ? min(cnt[nn], ELL_CAP) : 0;
    const unsigned* ep = pairs + ((size_t)nn << ELL_SHIFT);
    const int cbase = q * C;          // byte offset q*16: 16B-aligned

    float acc[C];
#pragma unroll
    for (int c = 0; c < C; ++c) acc[c] = 0.f;

    int i = 0;
    for (; i + 5 < end; i += 6) {
        uint2 pa = *(const uint2*)(ep + i);
        uint2 pb = *(const uint2*)(ep + i + 2);
        uint2 pc = *(const uint2*)(ep + i + 4);
        float w0 = (float)(pa.x >> 16) * EW_INV;
        float w1 = (float)(pa.y >> 16) * EW_INV;
        float w2 = (float)(pb.x >> 16) * EW_INV;
        float w3 = (float)(pb.y >> 16) * EW_INV;
        float w4 = (float)(pc.x >> 16) * EW_INV;
        float w5 = (float)(pc.y >> 16) * EW_INV;
        uint4 v0 = *(const uint4*)(h + (size_t)(pa.x & 0xFFFFu) * D + cbase);
        uint4 v1 = *(const uint4*)(h + (size_t)(pa.y & 0xFFFFu) * D + cbase);
        uint4 v2 = *(const uint4*)(h + (size_t)(pb.x & 0xFFFFu) * D + cbase);
        uint4 v3 = *(const uint4*)(h + (size_t)(pb.y & 0xFFFFu) * D + cbase);
        uint4 v4 = *(const uint4*)(h + (size_t)(pc.x & 0xFFFFu) * D + cbase);
        uint4 v5 = *(const uint4*)(h + (size_t)(pc.y & 0xFFFFu) * D + cbase);
        FMA8(0, v0, w0)
        FMA8(0, v1, w1)
        FMA8(0, v2, w2)
        FMA8(0, v3, w3)
        FMA8(0, v4, w4)
        FMA8(0, v5, w5)
    }
    for (; i < end; ++i) {
        unsigned p = ep[i];
        float w = (float)(p >> 16) * EW_INV;
        uint4 v = *(const uint4*)(h + (size_t)(p & 0xFFFFu) * D + cbase);
        FMA8(0, v, w)
    }

    float v[C];
#pragma unroll
    for (int c = 0; c < C; ++c) v[c] = acc[c] + b3[cbase + c];
    float m = v[0];
#pragma unroll
    for (int c = 1; c < C; ++c) m = fmaxf(m, v[c]);
    m = fmaxf(m, __shfl_xor(m, 1));
    m = fmaxf(m, __shfl_xor(m, 2));
    m = fmaxf(m, __shfl_xor(m, 4));
    float s = 0.f;
#pragma unroll
    for (int c = 0; c < C; ++c) s += expf(v[c] - m);
    s += __shfl_xor(s, 1);
    s += __shfl_xor(s, 2);
    s += __shfl_xor(s, 4);
    float l = m + logf(s);
    if (valid) {
        float4 o0 = make_float4(v[0] - l, v[1] - l, v[2] - l, v[3] - l);
        float4 o1 = make_float4(v[4] - l, v[5] - l, v[6] - l, v[7] - l);
        float* dst = outf + (size_t)n * D + cbase;
        *(float4*)(dst) = o0;
        *(float4*)(dst + 4) = o1;
    }
}

extern "C" void kernel_launch(void* const* d_in, const int* in_sizes, int n_in,
                              void* d_out, int out_size, void* d_ws, size_t ws_size,
                              hipStream_t stream) {
    const float* x   = (const float*)d_in[0];
    const float* ew  = (const float*)d_in[1];
    const int*   row = (const int*)d_in[2];
    const int*   col = (const int*)d_in[3];
    const float* W1  = (const float*)d_in[4];
    // b1 = d_in[5], b2 = d_in[7]: cancel inside BatchNorm (see gemm_mfma).
    const float* W2  = (const float*)d_in[6];
    const float* W3  = (const float*)d_in[8];
    const float* b3  = (const float*)d_in[9];
    const float* g1  = (const float*)d_in[10];
    const float* be1 = (const float*)d_in[11];
    const float* g2  = (const float*)d_in[12];
    const float* be2 = (const float*)d_in[13];
    float* out = (float*)d_out;

    // Workspace layout:
    // B bf16[N*96] | A bf16[N*96] | Wt1|Wt2|Wt3 bf16 | pairs uint[N*64] |
    // cnt[N] | stats1[4*192] | stats2[4*192]
    unsigned short* B      = (unsigned short*)d_ws;
    unsigned short* A      = B + (size_t)N_NODES * HID_C;
    unsigned short* Wt1    = A + (size_t)N_NODES * HID_C;
    unsigned short* Wt2    = Wt1 + IN_C * HID_C;
    unsigned short* Wt3    = Wt2 + HID_C * HID_C;
    unsigned int*   pairs  = (unsigned int*)(Wt3 + HID_C * OUT_C);
    int*            cnt    = (int*)(pairs + ((size_t)N_NODES << ELL_SHIFT));
    float*          stats1 = (float*)(cnt + N_NODES);
    float*          stats2 = stats1 + ST_SLICES * 2 * HID_C;

    const int T = 256;
    const int gridE  = (N_EDGES + T - 1) / T;        // 3125 edge chunks
    const int gridG  = (N_NODES + 63) / 64;          // 782 gemm tiles
    const int gridA9 = (N_NODES + 19) / 20;          // 2500 agg96 blocks
    const int gridA6 = (N_NODES + 31) / 32;          // 1563 agg64 blocks
    const int gridP  = (N_NODES + T - 1) / T;

    // ---- Prep + fill (standalone: keeps the XCD round-robin intact) ----
    prep_all<<<gridP, T, 0, stream>>>(W1, W2, W3, Wt1, Wt2, Wt3, cnt, stats1);
    fill_ell<<<gridE * NGRP, T, 0, stream>>>(row, col, ew, cnt, pairs);

    // ---- Layer 1: gemm(128->96); agg(+BN1 stats) ----
    gemm_mfma<IN_C, HID_C, false, false><<<gridG, T, 0, stream>>>(
        x, Wt1, nullptr, nullptr, nullptr, A, N_NODES);
    agg96<<<gridA9, T, 0, stream>>>(A, cnt, pairs, B, stats1);

    // ---- Layer 2: gemm fuses BN1 finalize+apply+ReLU; agg(+BN2 stats) ----
    gemm_mfma<HID_C, HID_C, true, true><<<gridG, T, 0, stream>>>(
        B, Wt2, stats1, g1, be1, A, N_NODES);
    agg96<<<gridA9, T, 0, stream>>>(A, cnt, pairs, B, stats2);

    // ---- Layer 3: gemm fuses BN2; agg fuses +b3 and log_softmax -> out ----
    gemm_mfma<HID_C, OUT_C, true, true><<<gridG, T, 0, stream>>>(
        B, Wt3, stats2, g2, be2, A, N_NODES);
    agg64_lsm<<<gridA6, T, 0, stream>>>(A, cnt, pairs, out, b3);
}

// Round 14
// 256.194 us; speedup vs baseline: 1.2579x; 1.2563x over previous
//
#include <hip/hip_runtime.h>
#include <hip/hip_bf16.h>
#include <math.h>

#define N_NODES 50000
#define N_EDGES 800000
#define IN_C 128
#define HID_C 96
#define OUT_C 64
#define BN_EPS 1e-5f

// ELL edge storage: 64 slots/row. deg ~ Poisson(16); P(deg>64) ~ 1e-17 —
// slot>=64 is guarded (skip) to protect memory, never expected to fire.
#define ELL_SHIFT 6
#define ELL_CAP   64

// XCD routing for the ELL fill (R13 winner).
#define NGRP 8
#define GRP_ROWS ((N_NODES + NGRP - 1) / NGRP)   // 6250

// Packed ELL entry: col in low 16 bits (N_NODES < 65536), edge weight as
// 16-bit fixed point in high bits (ew in [0,1); abs err 7.6e-6).
#define EW_SCALE 65535.0f
#define EW_INV   (1.0f / 65535.0f)

// BN stats atomic slicing: 4 slices cut per-address atomic chains 4x.
#define ST_SLICES 4

typedef __attribute__((ext_vector_type(8))) short short8;   // 8 bf16 = 4 VGPRs
typedef __attribute__((ext_vector_type(4))) float f32x4;    // MFMA acc

static __device__ __forceinline__ unsigned short f2b(float f) {
    __hip_bfloat16 b = __float2bfloat16(f);   // RNE
    return *reinterpret_cast<unsigned short*>(&b);
}
static __device__ __forceinline__ float b2f(unsigned short u) {
    return __uint_as_float((unsigned)u << 16);  // exact
}
static __device__ __forceinline__ unsigned pack2(float a, float b) {
    return (unsigned)f2b(a) | ((unsigned)f2b(b) << 16);
}

// Unpack 8 bf16 from a uint4 / 4 bf16 from a uint2, FMA into acc[B..].
#define FMA8(B, V, W)                                          \
    acc[(B) + 0] += (W) * __uint_as_float((V).x << 16);        \
    acc[(B) + 1] += (W) * __uint_as_float((V).x & 0xffff0000u);\
    acc[(B) + 2] += (W) * __uint_as_float((V).y << 16);        \
    acc[(B) + 3] += (W) * __uint_as_float((V).y & 0xffff0000u);\
    acc[(B) + 4] += (W) * __uint_as_float((V).z << 16);        \
    acc[(B) + 5] += (W) * __uint_as_float((V).z & 0xffff0000u);\
    acc[(B) + 6] += (W) * __uint_as_float((V).w << 16);        \
    acc[(B) + 7] += (W) * __uint_as_float((V).w & 0xffff0000u);

#define FMA4(B, V, W)                                          \
    acc[(B) + 0] += (W) * __uint_as_float((V).x << 16);        \
    acc[(B) + 1] += (W) * __uint_as_float((V).x & 0xffff0000u);\
    acc[(B) + 2] += (W) * __uint_as_float((V).y << 16);        \
    acc[(B) + 3] += (W) * __uint_as_float((V).y & 0xffff0000u);

// ---------------------------------------------------------------------------
// Prep (single launch): W[K][J] fp32 -> Wt[J][K] bf16 for all layers, zero
// the ELL counters, zero BN stats (2 buffers x 4 slices x 2*96 floats).
// ---------------------------------------------------------------------------
__global__ void prep_all(const float* __restrict__ W1, const float* __restrict__ W2,
                         const float* __restrict__ W3,
                         unsigned short* __restrict__ Wt1,
                         unsigned short* __restrict__ Wt2,
                         unsigned short* __restrict__ Wt3,
                         int* __restrict__ cnt, float* __restrict__ stats) {
    int i = blockIdx.x * blockDim.x + threadIdx.x;
    const int n1 = IN_C * HID_C, n2 = HID_C * HID_C, n3 = HID_C * OUT_C;
    if (i < n1) {
        int j = i / IN_C, k = i % IN_C;
        Wt1[i] = f2b(W1[k * HID_C + j]);
    } else if (i < n1 + n2) {
        int t = i - n1, j = t / HID_C, k = t % HID_C;
        Wt2[t] = f2b(W2[k * HID_C + j]);
    } else if (i < n1 + n2 + n3) {
        int t = i - n1 - n2, j = t / HID_C, k = t % HID_C;
        Wt3[t] = f2b(W3[k * OUT_C + j]);
    }
    if (i < N_NODES) cnt[i] = 0;
    if (i < 2 * ST_SLICES * 2 * HID_C) stats[i] = 0.f;   // stats1|stats2
}

// ---------------------------------------------------------------------------
// ELL fill, XCD-routed (R13 winner; fill 53us -> under the 43us prof floor).
// ---------------------------------------------------------------------------
__global__ __launch_bounds__(256)
void fill_ell(const int* __restrict__ row, const int* __restrict__ col,
              const float* __restrict__ ew, int* __restrict__ cnt,
              unsigned int* __restrict__ pairs) {
    int g = blockIdx.x & (NGRP - 1);          // row-group -> XCD (heuristic)
    int e = (blockIdx.x >> 3) * 256 + threadIdx.x;
    if (e >= N_EDGES) return;
    int r = row[e];
    int lo = g * GRP_ROWS;
    if ((unsigned)(r - lo) >= (unsigned)GRP_ROWS) return;   // not my group
    int slot = atomicAdd(&cnt[r], 1);
    if (slot < ELL_CAP) {
        unsigned wq = (unsigned)(ew[e] * EW_SCALE + 0.5f);  // [0,1) -> u16
        pairs[((size_t)r << ELL_SHIFT) + slot] = (wq << 16) | (unsigned)col[e];
    }
}

// ---------------------------------------------------------------------------
// MFMA GEMM (R14/R19, unchanged): h[N,J] = x[N,K] @ W[K,J], bf16 LDS
// operands, fp32 accumulate, row-major bf16 h output. XBF16: input table is
// bf16 (layers 2,3); else fp32 (layer 1). Block = 256 threads; tile 64 x J.
// mfma_f32_16x16x32_bf16 layouts (HW-verified):
//   A: lane holds X[m=lane&15][k=(lane>>4)*8+j]
//   B: lane holds W[k=(lane>>4)*8+j][n=lane&15]
//   D: lane,reg r -> row m=(lane>>4)*4+r, col n=lane&15
// APPLY: previous layer's BN finalize+apply+ReLU fused into x staging
// (conv bias cancels inside BN); stats arrive as ST_SLICES partials.
// ---------------------------------------------------------------------------
template <int K, int J, bool APPLY, bool XBF16>
__global__ __launch_bounds__(256)
void gemm_mfma(const void* __restrict__ xin,
               const unsigned short* __restrict__ Wt,  // [J][K] bf16
               const float* __restrict__ stats,
               const float* __restrict__ gamma,
               const float* __restrict__ beta,
               unsigned short* __restrict__ h, int N) {
    constexpr int MT = 64;
    constexpr int SK = K + 8;
    constexpr int NT = J / 16;
    __shared__ unsigned short Xs[MT * SK];
    __shared__ unsigned short Ws[J * SK];
    __shared__ float scsh_s[APPLY ? 2 * K : 2];

    int tid = threadIdx.x;
    int tileBase = blockIdx.x * MT;

    if (APPLY) {
        if (tid < K) {
            float s = 0.f, sq = 0.f;
#pragma unroll
            for (int sl = 0; sl < ST_SLICES; ++sl) {
                s  += stats[sl * 2 * K + tid];
                sq += stats[sl * 2 * K + K + tid];
            }
            const float invN = 1.f / N_NODES;
            float mean = s * invN;
            float var = sq * invN - mean * mean;
            float sc = gamma[tid] * rsqrtf(var + BN_EPS);
            scsh_s[tid] = sc;
            scsh_s[K + tid] = beta[tid] - mean * sc;
        }
        __syncthreads();
    }

    if (XBF16) {
        const unsigned short* xb = (const unsigned short*)xin;
        for (int i = tid; i < MT * (K / 8); i += 256) {
            int node = i / (K / 8), kq = i % (K / 8);
            int gn = min(tileBase + node, N - 1);
            const unsigned short* src = xb + (size_t)gn * K + kq * 8;
            ushort4 u0 = *(const ushort4*)(src);
            ushort4 u1 = *(const ushort4*)(src + 4);
            if (APPLY) {
                int kb = kq * 8;
                float v0 = fmaxf(b2f(u0.x) * scsh_s[kb + 0] + scsh_s[K + kb + 0], 0.f);
                float v1 = fmaxf(b2f(u0.y) * scsh_s[kb + 1] + scsh_s[K + kb + 1], 0.f);
                float v2 = fmaxf(b2f(u0.z) * scsh_s[kb + 2] + scsh_s[K + kb + 2], 0.f);
                float v3 = fmaxf(b2f(u0.w) * scsh_s[kb + 3] + scsh_s[K + kb + 3], 0.f);
                float v4 = fmaxf(b2f(u1.x) * scsh_s[kb + 4] + scsh_s[K + kb + 4], 0.f);
                float v5 = fmaxf(b2f(u1.y) * scsh_s[kb + 5] + scsh_s[K + kb + 5], 0.f);
                float v6 = fmaxf(b2f(u1.z) * scsh_s[kb + 6] + scsh_s[K + kb + 6], 0.f);
                float v7 = fmaxf(b2f(u1.w) * scsh_s[kb + 7] + scsh_s[K + kb + 7], 0.f);
                u0 = make_ushort4(f2b(v0), f2b(v1), f2b(v2), f2b(v3));
                u1 = make_ushort4(f2b(v4), f2b(v5), f2b(v6), f2b(v7));
            }
            *(ushort4*)&Xs[node * SK + kq * 8] = u0;
            *(ushort4*)&Xs[node * SK + kq * 8 + 4] = u1;
        }
    } else {
        const float* xf = (const float*)xin;
        for (int i = tid; i < MT * (K / 4); i += 256) {
            int node = i / (K / 4), kq = i % (K / 4);
            int gn = min(tileBase + node, N - 1);
            float4 v = *(const float4*)(xf + (size_t)gn * K + kq * 4);
            ushort4 o = make_ushort4(f2b(v.x), f2b(v.y), f2b(v.z), f2b(v.w));
            *(ushort4*)&Xs[node * SK + kq * 4] = o;
        }
    }
    for (int i = tid; i < J * (K / 4); i += 256) {
        int j = i / (K / 4), kq = i % (K / 4);
        *(ushort4*)&Ws[j * SK + kq * 4] =
            *(const ushort4*)(Wt + (size_t)j * K + kq * 4);
    }
    __syncthreads();

    int lane = tid & 63;
    int w = tid >> 6;
    int m16 = lane & 15;
    int quad = lane >> 4;

    f32x4 acc[NT];
#pragma unroll
    for (int nt = 0; nt < NT; ++nt) acc[nt] = (f32x4){0.f, 0.f, 0.f, 0.f};

    const unsigned short* xrow = &Xs[(w * 16 + m16) * SK];
#pragma unroll
    for (int k0 = 0; k0 < K; k0 += 32) {
        short8 a = *(const short8*)(xrow + k0 + quad * 8);
#pragma unroll
        for (int nt = 0; nt < NT; ++nt) {
            short8 b = *(const short8*)&Ws[(nt * 16 + m16) * SK + k0 + quad * 8];
            acc[nt] = __builtin_amdgcn_mfma_f32_16x16x32_bf16(a, b, acc[nt], 0, 0, 0);
        }
    }

#pragma unroll
    for (int nt = 0; nt < NT; ++nt) {
#pragma unroll
        for (int r = 0; r < 4; ++r) {
            int node = tileBase + w * 16 + quad * 4 + r;
            if (node < N)
                h[(size_t)node * J + nt * 16 + m16] = f2b(acc[nt][r]);
        }
    }
}

// ---------------------------------------------------------------------------
// 96-ch aggregation (R17 structure + R19 6-edge unroll; 257.0us verified).
// Agg ledger CLOSED after 5 structural attacks: TPN=8 (win) / parity-16
// (-15us) / MLP-6 (null) / ch-slice (-73us) / 12-lane-single-load (-65us,
// compiler serializes loads at VGPR=28 regardless of launch_bounds budget).
// FETCH ~70MB is layout-invariant -> the random gather is at the L3
// effective-throughput floor (~40us/agg). 8 threads/node (C=12), 32
// nodes/block, grid 1563. BN stats fused (masks 8/16/32 -> LDS -> sliced
// atomicAdd).
// ---------------------------------------------------------------------------
__global__ __launch_bounds__(256, 6)
void agg96(const unsigned short* __restrict__ h,     // row-major [N][96]
           const int* __restrict__ cnt,
           const unsigned int* __restrict__ pairs,
           unsigned short* __restrict__ outb,        // row-major [N][96]
           float* __restrict__ stats) {
    constexpr int D = HID_C, C = 12;
    int tid = threadIdx.x;
    int q = tid & 7;
    int nloc = tid >> 3;              // 0..31
    int n = blockIdx.x * 32 + nloc;
    bool valid = n < N_NODES;
    int nn = valid ? n : N_NODES - 1;
    int end = valid ? min(cnt[nn], ELL_CAP) : 0;
    const unsigned* ep = pairs + ((size_t)nn << ELL_SHIFT);
    const int cbase = q * C;          // byte offset q*24: 8B-aligned

    float acc[C];
#pragma unroll
    for (int c = 0; c < C; ++c) acc[c] = 0.f;

    int i = 0;
    for (; i + 5 < end; i += 6) {
        uint2 pa = *(const uint2*)(ep + i);         // edges i, i+1
        uint2 pb = *(const uint2*)(ep + i + 2);     // edges i+2, i+3
        uint2 pc = *(const uint2*)(ep + i + 4);     // edges i+4, i+5
        float w0 = (float)(pa.x >> 16) * EW_INV;
        float w1 = (float)(pa.y >> 16) * EW_INV;
        float w2 = (float)(pb.x >> 16) * EW_INV;
        float w3 = (float)(pb.y >> 16) * EW_INV;
        float w4 = (float)(pc.x >> 16) * EW_INV;
        float w5 = (float)(pc.y >> 16) * EW_INV;
        const unsigned short* r0 = h + (size_t)(pa.x & 0xFFFFu) * D + cbase;
        const unsigned short* r1 = h + (size_t)(pa.y & 0xFFFFu) * D + cbase;
        const unsigned short* r2 = h + (size_t)(pb.x & 0xFFFFu) * D + cbase;
        const unsigned short* r3 = h + (size_t)(pb.y & 0xFFFFu) * D + cbase;
        const unsigned short* r4 = h + (size_t)(pc.x & 0xFFFFu) * D + cbase;
        const unsigned short* r5 = h + (size_t)(pc.y & 0xFFFFu) * D + cbase;
        // Issue all 18 loads before any FMA (MLP).
        uint2 a0 = *(const uint2*)(r0), a1 = *(const uint2*)(r0 + 4), a2 = *(const uint2*)(r0 + 8);
        uint2 b0 = *(const uint2*)(r1), b1 = *(const uint2*)(r1 + 4), b2 = *(const uint2*)(r1 + 8);
        uint2 c0 = *(const uint2*)(r2), c1 = *(const uint2*)(r2 + 4), c2 = *(const uint2*)(r2 + 8);
        uint2 d0 = *(const uint2*)(r3), d1 = *(const uint2*)(r3 + 4), d2 = *(const uint2*)(r3 + 8);
        uint2 e0 = *(const uint2*)(r4), e1 = *(const uint2*)(r4 + 4), e2 = *(const uint2*)(r4 + 8);
        uint2 f0 = *(const uint2*)(r5), f1 = *(const uint2*)(r5 + 4), f2 = *(const uint2*)(r5 + 8);
        FMA4(0, a0, w0) FMA4(4, a1, w0) FMA4(8, a2, w0)
        FMA4(0, b0, w1) FMA4(4, b1, w1) FMA4(8, b2, w1)
        FMA4(0, c0, w2) FMA4(4, c1, w2) FMA4(8, c2, w2)
        FMA4(0, d0, w3) FMA4(4, d1, w3) FMA4(8, d2, w3)
        FMA4(0, e0, w4) FMA4(4, e1, w4) FMA4(8, e2, w4)
        FMA4(0, f0, w5) FMA4(4, f1, w5) FMA4(8, f2, w5)
    }
    for (; i < end; ++i) {
        unsigned p = ep[i];
        float w = (float)(p >> 16) * EW_INV;
        const unsigned short* r0 = h + (size_t)(p & 0xFFFFu) * D + cbase;
        uint2 a0 = *(const uint2*)(r0), a1 = *(const uint2*)(r0 + 4), a2 = *(const uint2*)(r0 + 8);
        FMA4(0, a0, w) FMA4(4, a1, w) FMA4(8, a2, w)
    }

    // Round to bf16 in place (stats must see the rounded values).
#pragma unroll
    for (int c = 0; c < C; ++c) acc[c] = b2f(f2b(acc[c]));

    if (valid) {
        unsigned short* dst = outb + (size_t)n * D + cbase;
        uint2 o0, o1, o2;
        o0.x = pack2(acc[0], acc[1]);   o0.y = pack2(acc[2], acc[3]);
        o1.x = pack2(acc[4], acc[5]);   o1.y = pack2(acc[6], acc[7]);
        o2.x = pack2(acc[8], acc[9]);   o2.y = pack2(acc[10], acc[11]);
        *(uint2*)(dst) = o0; *(uint2*)(dst + 4) = o1; *(uint2*)(dst + 8) = o2;
    }

    // BN stats: butterfly over the wave's 8 nodes (masks 8/16/32), then LDS
    // across the 4 waves, then sliced global atomicAdd.
    __shared__ float shS[4 * 8 * C];
    __shared__ float shQ[4 * 8 * C];
    int lane = tid & 63, wv = tid >> 6;
#pragma unroll
    for (int c = 0; c < C; ++c) {
        float s = acc[c];             // invalid nodes contribute 0
        float sq = s * s;
        s  += __shfl_xor(s, 8);  sq += __shfl_xor(sq, 8);
        s  += __shfl_xor(s, 16); sq += __shfl_xor(sq, 16);
        s  += __shfl_xor(s, 32); sq += __shfl_xor(sq, 32);
        if (lane < 8) { shS[(wv * 8 + lane) * C + c] = s;
                        shQ[(wv * 8 + lane) * C + c] = sq; }
    }
    __syncthreads();
    if (tid < D) {
        int qq = tid / C, cl = tid % C;   // global channel == tid
        float S = 0.f, Q = 0.f;
#pragma unroll
        for (int w2 = 0; w2 < 4; ++w2) {
            S += shS[(w2 * 8 + qq) * C + cl];
            Q += shQ[(w2 * 8 + qq) * C + cl];
        }
        int sl = blockIdx.x & (ST_SLICES - 1);
        atomicAdd(&stats[sl * 2 * D + tid], S);
        atomicAdd(&stats[sl * 2 * D + D + tid], Q);
    }
}

// ---------------------------------------------------------------------------
// Layer-3 aggregation + b3 + log_softmax (R19: 8 threads/node, C=8,
// 32 nodes/block, 6-edge unroll — one uint4/edge is already the
// 2-requests/edge minimum for 128B rows).
// ---------------------------------------------------------------------------
__global__ __launch_bounds__(256, 6)
void agg64_lsm(const unsigned short* __restrict__ h,  // row-major [N][64]
               const int* __restrict__ cnt,
               const unsigned int* __restrict__ pairs,
               float* __restrict__ outf,
               const float* __restrict__ b3) {
    constexpr int D = OUT_C, C = 8;
    int tid = threadIdx.x;
    int q = tid & 7;
    int nloc = tid >> 3;              // 0..31
    int n = blockIdx.x * 32 + nloc;
    bool valid = n < N_NODES;
    int nn = valid ? n : N_NODES - 1;
    int end = valid ? min(cnt[nn], ELL_CAP) : 0;
    const unsigned* ep = pairs + ((size_t)nn << ELL_SHIFT);
    const int cbase = q * C;          // byte offset q*16: 16B-aligned

    float acc[C];
#pragma unroll
    for (int c = 0; c < C; ++c) acc[c] = 0.f;

    int i = 0;
    for (; i + 5 < end; i += 6) {
        uint2 pa = *(const uint2*)(ep + i);
        uint2 pb = *(const uint2*)(ep + i + 2);
        uint2 pc = *(const uint2*)(ep + i + 4);
        float w0 = (float)(pa.x >> 16) * EW_INV;
        float w1 = (float)(pa.y >> 16) * EW_INV;
        float w2 = (float)(pb.x >> 16) * EW_INV;
        float w3 = (float)(pb.y >> 16) * EW_INV;
        float w4 = (float)(pc.x >> 16) * EW_INV;
        float w5 = (float)(pc.y >> 16) * EW_INV;
        uint4 v0 = *(const uint4*)(h + (size_t)(pa.x & 0xFFFFu) * D + cbase);
        uint4 v1 = *(const uint4*)(h + (size_t)(pa.y & 0xFFFFu) * D + cbase);
        uint4 v2 = *(const uint4*)(h + (size_t)(pb.x & 0xFFFFu) * D + cbase);
        uint4 v3 = *(const uint4*)(h + (size_t)(pb.y & 0xFFFFu) * D + cbase);
        uint4 v4 = *(const uint4*)(h + (size_t)(pc.x & 0xFFFFu) * D + cbase);
        uint4 v5 = *(const uint4*)(h + (size_t)(pc.y & 0xFFFFu) * D + cbase);
        FMA8(0, v0, w0)
        FMA8(0, v1, w1)
        FMA8(0, v2, w2)
        FMA8(0, v3, w3)
        FMA8(0, v4, w4)
        FMA8(0, v5, w5)
    }
    for (; i < end; ++i) {
        unsigned p = ep[i];
        float w = (float)(p >> 16) * EW_INV;
        uint4 v = *(const uint4*)(h + (size_t)(p & 0xFFFFu) * D + cbase);
        FMA8(0, v, w)
    }

    float v[C];
#pragma unroll
    for (int c = 0; c < C; ++c) v[c] = acc[c] + b3[cbase + c];
    float m = v[0];
#pragma unroll
    for (int c = 1; c < C; ++c) m = fmaxf(m, v[c]);
    m = fmaxf(m, __shfl_xor(m, 1));
    m = fmaxf(m, __shfl_xor(m, 2));
    m = fmaxf(m, __shfl_xor(m, 4));
    float s = 0.f;
#pragma unroll
    for (int c = 0; c < C; ++c) s += expf(v[c] - m);
    s += __shfl_xor(s, 1);
    s += __shfl_xor(s, 2);
    s += __shfl_xor(s, 4);
    float l = m + logf(s);
    if (valid) {
        float4 o0 = make_float4(v[0] - l, v[1] - l, v[2] - l, v[3] - l);
        float4 o1 = make_float4(v[4] - l, v[5] - l, v[6] - l, v[7] - l);
        float* dst = outf + (size_t)n * D + cbase;
        *(float4*)(dst) = o0;
        *(float4*)(dst + 4) = o1;
    }
}

extern "C" void kernel_launch(void* const* d_in, const int* in_sizes, int n_in,
                              void* d_out, int out_size, void* d_ws, size_t ws_size,
                              hipStream_t stream) {
    const float* x   = (const float*)d_in[0];
    const float* ew  = (const float*)d_in[1];
    const int*   row = (const int*)d_in[2];
    const int*   col = (const int*)d_in[3];
    const float* W1  = (const float*)d_in[4];
    // b1 = d_in[5], b2 = d_in[7]: cancel inside BatchNorm (see gemm_mfma).
    const float* W2  = (const float*)d_in[6];
    const float* W3  = (const float*)d_in[8];
    const float* b3  = (const float*)d_in[9];
    const float* g1  = (const float*)d_in[10];
    const float* be1 = (const float*)d_in[11];
    const float* g2  = (const float*)d_in[12];
    const float* be2 = (const float*)d_in[13];
    float* out = (float*)d_out;

    // Workspace layout:
    // B bf16[N*96] | A bf16[N*96] | Wt1|Wt2|Wt3 bf16 | pairs uint[N*64] |
    // cnt[N] | stats1[4*192] | stats2[4*192]
    unsigned short* B      = (unsigned short*)d_ws;
    unsigned short* A      = B + (size_t)N_NODES * HID_C;
    unsigned short* Wt1    = A + (size_t)N_NODES * HID_C;
    unsigned short* Wt2    = Wt1 + IN_C * HID_C;
    unsigned short* Wt3    = Wt2 + HID_C * HID_C;
    unsigned int*   pairs  = (unsigned int*)(Wt3 + HID_C * OUT_C);
    int*            cnt    = (int*)(pairs + ((size_t)N_NODES << ELL_SHIFT));
    float*          stats1 = (float*)(cnt + N_NODES);
    float*          stats2 = stats1 + ST_SLICES * 2 * HID_C;

    const int T = 256;
    const int gridE  = (N_EDGES + T - 1) / T;        // 3125 edge chunks
    const int gridG  = (N_NODES + 63) / 64;          // 782 gemm tiles
    const int gridA  = (N_NODES + 31) / 32;          // 1563 agg blocks
    const int gridP  = (N_NODES + T - 1) / T;

    // ---- Prep + fill ----
    prep_all<<<gridP, T, 0, stream>>>(W1, W2, W3, Wt1, Wt2, Wt3, cnt, stats1);
    fill_ell<<<gridE * NGRP, T, 0, stream>>>(row, col, ew, cnt, pairs);

    // ---- Layer 1: gemm(128->96); agg(+BN1 stats) ----
    gemm_mfma<IN_C, HID_C, false, false><<<gridG, T, 0, stream>>>(
        x, Wt1, nullptr, nullptr, nullptr, A, N_NODES);
    agg96<<<gridA, T, 0, stream>>>(A, cnt, pairs, B, stats1);

    // ---- Layer 2: gemm fuses BN1 finalize+apply+ReLU; agg(+BN2 stats) ----
    gemm_mfma<HID_C, HID_C, true, true><<<gridG, T, 0, stream>>>(
        B, Wt2, stats1, g1, be1, A, N_NODES);
    agg96<<<gridA, T, 0, stream>>>(A, cnt, pairs, B, stats2);

    // ---- Layer 3: gemm fuses BN2; agg fuses +b3 and log_softmax -> out ----
    gemm_mfma<HID_C, OUT_C, true, true><<<gridG, T, 0, stream>>>(
        B, Wt3, stats2, g2, be2, A, N_NODES);
    agg64_lsm<<<gridA, T, 0, stream>>>(A, cnt, pairs, out, b3);
}